// Round 3
// baseline (8606.706 us; speedup 1.0000x reference)
//
#include <hip/hip_runtime.h>
#include <cstddef>
#include <cstdint>
#include <math.h>

#define BB   4
#define TT   2048
#define CCH  1024
#define HH   16
#define DD   64
#define CSZ  16
#define NTC  128
#define EPSF 1e-5f

typedef float v2f __attribute__((ext_vector_type(2)));

__device__ __forceinline__ float wave_sum(float v) {
#pragma unroll
  for (int off = 32; off > 0; off >>= 1) v += __shfl_xor(v, off, 64);
  return v;
}

// C = A(lda) @ W + bias ; A: MxK row-major w/ stride lda, W: KxN row-major, C: MxN (ldc = N)
__global__ __launch_bounds__(256) void gemm_f32(
    const float* __restrict__ A, int lda,
    const float* __restrict__ W,
    const float* __restrict__ bias,
    float* __restrict__ C, int M, int N, int K) {
  __shared__ float As[16][132];
  __shared__ float Bs[16][128];
  const int tid  = threadIdx.x;
  const int row0 = blockIdx.y * 128;
  const int col0 = blockIdx.x * 128;
  const int ty = tid >> 4;
  const int tx = tid & 15;
  const int a_r = tid >> 2;
  const int a_k = (tid & 3) << 2;
  const int b_r = tid >> 5;
  const int b_c = (tid & 31) << 2;

  float acc[8][8];
#pragma unroll
  for (int i = 0; i < 8; i++)
#pragma unroll
    for (int j = 0; j < 8; j++) acc[i][j] = 0.f;

  for (int k0 = 0; k0 < K; k0 += 16) {
#pragma unroll
    for (int i = 0; i < 2; i++) {
      int r = a_r + i * 64;
      float4 av = *(const float4*)(A + (size_t)(row0 + r) * lda + (k0 + a_k));
      As[a_k + 0][r] = av.x;
      As[a_k + 1][r] = av.y;
      As[a_k + 2][r] = av.z;
      As[a_k + 3][r] = av.w;
    }
#pragma unroll
    for (int i = 0; i < 2; i++) {
      int r = b_r + i * 8;
      int gc = col0 + b_c;
      float4 bv = make_float4(0.f, 0.f, 0.f, 0.f);
      if (gc < N) bv = *(const float4*)(W + (size_t)(k0 + r) * N + gc);
      *(float4*)(&Bs[r][b_c]) = bv;
    }
    __syncthreads();
#pragma unroll
    for (int kk = 0; kk < 16; kk++) {
      float af[8], bf[8];
      *(float4*)&af[0] = *(const float4*)&As[kk][ty * 8];
      *(float4*)&af[4] = *(const float4*)&As[kk][ty * 8 + 4];
      *(float4*)&bf[0] = *(const float4*)&Bs[kk][tx * 8];
      *(float4*)&bf[4] = *(const float4*)&Bs[kk][tx * 8 + 4];
#pragma unroll
      for (int i = 0; i < 8; i++)
#pragma unroll
        for (int j = 0; j < 8; j++) acc[i][j] += af[i] * bf[j];
    }
    __syncthreads();
  }
#pragma unroll
  for (int i = 0; i < 8; i++) {
    int r = row0 + ty * 8 + i;
#pragma unroll
    for (int j0 = 0; j0 < 8; j0 += 4) {
      int cc = col0 + tx * 8 + j0;
      if (cc < N) {
        float4 ov;
        ov.x = acc[i][j0 + 0] + bias[cc + 0];
        ov.y = acc[i][j0 + 1] + bias[cc + 1];
        ov.z = acc[i][j0 + 2] + bias[cc + 2];
        ov.w = acc[i][j0 + 3] + bias[cc + 3];
        *(float4*)(C + (size_t)r * N + cc) = ov;
      }
    }
  }
}

__global__ __launch_bounds__(256) void normalize_qk(float* __restrict__ qkv) {
  const int idx = blockIdx.x * 4 + (threadIdx.x >> 6);
  const int l = threadIdx.x & 63;
  const int rowBT = idx >> 5;
  const int rem = idx & 31;
  const int which = rem >> 4;
  const int h = rem & 15;
  const size_t addr = (size_t)rowBT * 3072 + (size_t)which * 1024 + h * 64 + l;
  float v = qkv[addr];
  float ss = wave_sum(v * v);
  float nrm = sqrtf(ss);
  float sc = 1.f / fmaxf(nrm, 1e-12f);
  qkv[addr] = v * sc;
}

// Titans recurrence, single-wave version. grid = 64 (one block per (b,h)),
// block = 64 (one wave). Lane l owns S[:,l] and M[:,l] as 32 float2 pairs.
// k/q rows are read via wave-uniform global loads; all reductions are
// intra-wave shuffles. No LDS, no barriers.
__global__ __launch_bounds__(64) void titans_rec(
    float* __restrict__ qkv, const float* __restrict__ p,
    const float* __restrict__ w, const float* __restrict__ bparm) {
  const int bh = blockIdx.x;
  const int b = bh >> 4;
  const int h = bh & 15;
  const int l = threadIdx.x;

  const float w_l = w[h * DD + l];
  const float b_l = bparm[h * DD + l];

  float* qk = qkv + (size_t)(b * TT) * 3072 + h * DD;   // +0: q, +1024: k, +2048: v
  const float* pbase = p + (size_t)(b * TT) * 48 + h * 3;

  v2f S[32], M[32];
#pragma unroll
  for (int i = 0; i < 32; i++) { S[i] = (v2f){0.f, 0.f}; M[i] = (v2f){0.f, 0.f}; }

  for (int nt = 0; nt < NTC; nt++) {
    const int row0 = nt * CSZ;

    // per-lane v values (column l of the chunk's v tile), coalesced
    float vv[CSZ];
#pragma unroll 4
    for (int c = 0; c < CSZ; c++)
      vv[c] = qk[(size_t)(row0 + c) * 3072 + 2048 + l];

    // per-token gate scalars (lane-invariant loads; sigmoid computed per-lane)
    float th[CSZ], al[CSZ], et[CSZ];
#pragma unroll 4
    for (int t = 0; t < CSZ; t++) {
      const float* pr = pbase + (size_t)(row0 + t) * 48;
      float p0 = pr[0], p1 = pr[1], p2 = pr[2];
      th[t] = 1.f / (1.f + expf(-p0));
      al[t] = 1.f / (1.f + expf(-p1));
      et[t] = 1.f / (1.f + expf(-p2));
    }

    // ---- kh[c] = (k_c . S[:,l]) for all 16 rows; k row is wave-uniform ----
    float kh[CSZ];
#pragma unroll 2
    for (int c = 0; c < CSZ; c++) {
      const v2f* kr = (const v2f*)(qk + (size_t)(row0 + c) * 3072 + 1024);
      v2f acc0 = (v2f){0.f, 0.f}, acc1 = (v2f){0.f, 0.f};
#pragma unroll
      for (int i = 0; i < 32; i += 2) {
        acc0 += kr[i] * S[i];
        acc1 += kr[i + 1] * S[i + 1];
      }
      kh[c] = acc0.x + acc0.y + acc1.x + acc1.y;
    }

    // ---- LN forward + backward per row (intra-wave reductions) ----
    float dkh[CSZ];
#pragma unroll 4
    for (int c = 0; c < CSZ; c++) {
      float x = kh[c];
      float mu = wave_sum(x) * (1.f / 64.f);
      float xc = x - mu;
      float var = wave_sum(xc * xc) * (1.f / 64.f);
      float rstd = rsqrtf(var + EPSF);
      float xhat = xc * rstd;
      float dy = 2.f * (xhat * w_l + b_l - vv[c]);
      float wdy = dy * w_l;
      float c1 = wave_sum(xhat * wdy) * (1.f / 64.f);
      float c2 = wave_sum(wdy) * (1.f / 64.f);
      dkh[c] = (wdy - xhat * c1 - c2) * rstd;
    }

    // ---- token scan: M = et*M - (th*dkh_l)*k_r ; S = (1-al)*S + M ; o = q.S ----
    float o[CSZ];
#pragma unroll 1
    for (int t = 0; t < CSZ; t++) {
      const v2f* kr = (const v2f*)(qk + (size_t)(row0 + t) * 3072 + 1024);
      const v2f* qr = (const v2f*)(qk + (size_t)(row0 + t) * 3072);
      const float a = th[t] * dkh[t];
      const v2f av = (v2f){a, a};
      const v2f ev = (v2f){et[t], et[t]};
      const float oma = 1.f - al[t];
      const v2f ov = (v2f){oma, oma};
      v2f oacc0 = (v2f){0.f, 0.f}, oacc1 = (v2f){0.f, 0.f};
#pragma unroll
      for (int i = 0; i < 32; i += 2) {
        M[i] = ev * M[i] - av * kr[i];
        S[i] = ov * S[i] + M[i];
        oacc0 += qr[i] * S[i];
        M[i + 1] = ev * M[i + 1] - av * kr[i + 1];
        S[i + 1] = ov * S[i + 1] + M[i + 1];
        oacc1 += qr[i + 1] * S[i + 1];
      }
      o[t] = oacc0.x + oacc0.y + oacc1.x + oacc1.y;
    }

    // ---- final LN on o + store into the consumed v-slot ----
#pragma unroll 4
    for (int t = 0; t < CSZ; t++) {
      float x = o[t];
      float mu = wave_sum(x) * (1.f / 64.f);
      float xc = x - mu;
      float var = wave_sum(xc * xc) * (1.f / 64.f);
      float rstd = rsqrtf(var + EPSF);
      float y = xc * rstd * w_l + b_l;
      qk[(size_t)(row0 + t) * 3072 + 2048 + l] = y;
    }
  }
}

extern "C" void kernel_launch(void* const* d_in, const int* in_sizes, int n_in,
                              void* d_out, int out_size, void* d_ws, size_t ws_size,
                              hipStream_t stream) {
  const float* x      = (const float*)d_in[0];
  const float* W_attn = (const float*)d_in[1];
  const float* b_attn = (const float*)d_in[2];
  const float* W_parm = (const float*)d_in[3];
  const float* b_parm = (const float*)d_in[4];
  const float* W_proj = (const float*)d_in[5];
  const float* b_proj = (const float*)d_in[6];
  const float* w      = (const float*)d_in[7];
  const float* bb     = (const float*)d_in[8];
  float* out = (float*)d_out;

  const int M = BB * TT;        // 8192
  float* qkv = (float*)d_ws;                          // M x 3072
  float* pbf = qkv + (size_t)M * 3072;                // M x 48

  gemm_f32<<<dim3(3072 / 128, M / 128), 256, 0, stream>>>(x, CCH, W_attn, b_attn, qkv, M, 3072, CCH);
  gemm_f32<<<dim3(1, M / 128), 256, 0, stream>>>(x, CCH, W_parm, b_parm, pbf, M, 48, CCH);
  normalize_qk<<<(M * 2 * HH) / 4, 256, 0, stream>>>(qkv);
  titans_rec<<<BB * HH, 64, 0, stream>>>(qkv, pbf, w, bb);
  gemm_f32<<<dim3(CCH / 128, M / 128), 256, 0, stream>>>(qkv + 2048, 3072, W_proj, b_proj, out, M, CCH, CCH);
}

// Round 6
// 4303.743 us; speedup vs baseline: 1.9998x; 1.9998x over previous
//
#include <hip/hip_runtime.h>
#include <cstddef>
#include <cstdint>
#include <math.h>

#define BB   4
#define TT   2048
#define CCH  1024
#define HH   16
#define DD   64
#define CSZ  16
#define NTC  128
#define EPSF 1e-5f

typedef float v2f __attribute__((ext_vector_type(2)));
typedef short bf16x8 __attribute__((ext_vector_type(8)));
typedef float f32x4 __attribute__((ext_vector_type(4)));

__device__ __forceinline__ float wave_sum(float v) {
#pragma unroll
  for (int off = 32; off > 0; off >>= 1) v += __shfl_xor(v, off, 64);
  return v;
}

__device__ __forceinline__ unsigned short f2bf(float f) {  // RNE
  unsigned u = __float_as_uint(f);
  u = (u + 0x7FFFu + ((u >> 16) & 1u)) >> 16;
  return (unsigned short)u;
}
__device__ __forceinline__ float bf2f(unsigned short h) {
  return __uint_as_float(((unsigned)h) << 16);
}

__device__ __forceinline__ void glds16(const void* g, void* l) {
  __builtin_amdgcn_global_load_lds(
      (const __attribute__((address_space(1))) unsigned*)g,
      (__attribute__((address_space(3))) unsigned*)l, 16, 0, 0);
}

// ---------------- fp32 GEMM (param GEMM only, N=48) ----------
__global__ __launch_bounds__(256) void gemm_f32(
    const float* __restrict__ A, int lda,
    const float* __restrict__ W,
    const float* __restrict__ bias,
    float* __restrict__ C, int M, int N, int K) {
  __shared__ float As[16][132];
  __shared__ float Bs[16][128];
  const int tid  = threadIdx.x;
  const int row0 = blockIdx.y * 128;
  const int col0 = blockIdx.x * 128;
  const int ty = tid >> 4;
  const int tx = tid & 15;
  const int a_r = tid >> 2;
  const int a_k = (tid & 3) << 2;
  const int b_r = tid >> 5;
  const int b_c = (tid & 31) << 2;

  float acc[8][8];
#pragma unroll
  for (int i = 0; i < 8; i++)
#pragma unroll
    for (int j = 0; j < 8; j++) acc[i][j] = 0.f;

  for (int k0 = 0; k0 < K; k0 += 16) {
#pragma unroll
    for (int i = 0; i < 2; i++) {
      int r = a_r + i * 64;
      float4 av = *(const float4*)(A + (size_t)(row0 + r) * lda + (k0 + a_k));
      As[a_k + 0][r] = av.x;
      As[a_k + 1][r] = av.y;
      As[a_k + 2][r] = av.z;
      As[a_k + 3][r] = av.w;
    }
#pragma unroll
    for (int i = 0; i < 2; i++) {
      int r = b_r + i * 8;
      int gc = col0 + b_c;
      float4 bv = make_float4(0.f, 0.f, 0.f, 0.f);
      if (gc < N) bv = *(const float4*)(W + (size_t)(k0 + r) * N + gc);
      *(float4*)(&Bs[r][b_c]) = bv;
    }
    __syncthreads();
#pragma unroll
    for (int kk = 0; kk < 16; kk++) {
      float af[8], bf[8];
      *(float4*)&af[0] = *(const float4*)&As[kk][ty * 8];
      *(float4*)&af[4] = *(const float4*)&As[kk][ty * 8 + 4];
      *(float4*)&bf[0] = *(const float4*)&Bs[kk][tx * 8];
      *(float4*)&bf[4] = *(const float4*)&Bs[kk][tx * 8 + 4];
#pragma unroll
      for (int i = 0; i < 8; i++)
#pragma unroll
        for (int j = 0; j < 8; j++) acc[i][j] += af[i] * bf[j];
    }
    __syncthreads();
  }
#pragma unroll
  for (int i = 0; i < 8; i++) {
    int r = row0 + ty * 8 + i;
#pragma unroll
    for (int j0 = 0; j0 < 8; j0 += 4) {
      int cc = col0 + tx * 8 + j0;
      if (cc < N) {
        float4 ov;
        ov.x = acc[i][j0 + 0] + bias[cc + 0];
        ov.y = acc[i][j0 + 1] + bias[cc + 1];
        ov.z = acc[i][j0 + 2] + bias[cc + 2];
        ov.w = acc[i][j0 + 3] + bias[cc + 3];
        *(float4*)(C + (size_t)r * N + cc) = ov;
      }
    }
  }
}

// ---------------- split-precision MFMA GEMM:
// C(f32) = A(f32,[M][K]) @ B + bias, where B is pre-split transposed bf16:
// Bh/Bl = [N][K]. A is staged f32 to LDS, split hi/lo in-register (trunc).
// Error ~2^-16 relative (vs 2^-8 plain bf16).
__global__ __launch_bounds__(256) void gemm_split(
    const float* __restrict__ A,
    const unsigned short* __restrict__ Bh,
    const unsigned short* __restrict__ Bl,
    const float* __restrict__ bias,
    float* __restrict__ C, int M, int N, int K) {
  __shared__ float Asf[128 * 32];           // 16 KB
  __shared__ unsigned short Bsh[128 * 32];  // 8 KB
  __shared__ unsigned short Bsl[128 * 32];  // 8 KB
  const int tid = threadIdx.x;
  const int wv = tid >> 6, l = tid & 63;
  const int row0 = blockIdx.y * 128, col0 = blockIdx.x * 128;
  const int wm = (wv & 1) * 64, wn = (wv >> 1) * 64;
  const int sar = l >> 3, sac = (l & 7) * 4;   // A staging: 8 rows/instr, 4 f32/lane
  const int sbr = l >> 2, sbc = (l & 3) * 8;   // B staging: 16 rows/instr, 8 bf16/lane
  const int fr = l & 15, fq = (l >> 4) * 8;

  f32x4 acc[4][4];
#pragma unroll
  for (int i = 0; i < 4; i++)
#pragma unroll
    for (int j = 0; j < 4; j++) acc[i][j] = (f32x4){0.f, 0.f, 0.f, 0.f};

  for (int k0 = 0; k0 < K; k0 += 32) {
#pragma unroll
    for (int g = wv; g < 16; g += 4)
      glds16(A + (size_t)(row0 + g * 8 + sar) * K + k0 + sac, (char*)Asf + g * 1024);
#pragma unroll
    for (int g = wv; g < 8; g += 4) {
      glds16(Bh + (size_t)(col0 + g * 16 + sbr) * K + k0 + sbc, (char*)Bsh + g * 1024);
      glds16(Bl + (size_t)(col0 + g * 16 + sbr) * K + k0 + sbc, (char*)Bsl + g * 1024);
    }
    __syncthreads();

    bf16x8 ah[4], al[4], bh[4], bl[4];
#pragma unroll
    for (int mi = 0; mi < 4; mi++) {
      const float* ap = &Asf[(wm + mi * 16 + fr) * 32 + fq];
      float xf[8];
      *(f32x4*)&xf[0] = *(const f32x4*)ap;
      *(f32x4*)&xf[4] = *(const f32x4*)(ap + 4);
#pragma unroll
      for (int j = 0; j < 8; j++) {
        unsigned u = __float_as_uint(xf[j]);
        ah[mi][j] = (short)(u >> 16);                       // hi = trunc
        float r = xf[j] - __uint_as_float(u & 0xFFFF0000u); // exact residual
        al[mi][j] = (short)(__float_as_uint(r) >> 16);      // lo = trunc
      }
    }
#pragma unroll
    for (int ni = 0; ni < 4; ni++) {
      bh[ni] = *(const bf16x8*)&Bsh[(wn + ni * 16 + fr) * 32 + fq];
      bl[ni] = *(const bf16x8*)&Bsl[(wn + ni * 16 + fr) * 32 + fq];
    }
#pragma unroll
    for (int mi = 0; mi < 4; mi++)
#pragma unroll
      for (int ni = 0; ni < 4; ni++) {
        acc[mi][ni] = __builtin_amdgcn_mfma_f32_16x16x32_bf16(ah[mi], bh[ni], acc[mi][ni], 0, 0, 0);
        acc[mi][ni] = __builtin_amdgcn_mfma_f32_16x16x32_bf16(al[mi], bh[ni], acc[mi][ni], 0, 0, 0);
        acc[mi][ni] = __builtin_amdgcn_mfma_f32_16x16x32_bf16(ah[mi], bl[ni], acc[mi][ni], 0, 0, 0);
      }
    __syncthreads();
  }
  const int q = l >> 4;
#pragma unroll
  for (int mi = 0; mi < 4; mi++)
#pragma unroll
    for (int ni = 0; ni < 4; ni++) {
      int col = col0 + wn + ni * 16 + fr;
      float bs = bias[col];
#pragma unroll
      for (int r = 0; r < 4; r++) {
        int row = row0 + wm + mi * 16 + q * 4 + r;
        C[(size_t)row * N + col] = acc[mi][ni][r] + bs;
      }
    }
}

// ---------------- plain bf16 MFMA GEMM (proj): C = A @ Bt^T + bias.
// remap!=0: A's k-index c lives at short offset (c>>6)*128 + (c&63).
__global__ __launch_bounds__(256) void gemm_bf16(
    const unsigned short* __restrict__ A, int lda,
    const unsigned short* __restrict__ Bt,
    const float* __restrict__ bias,
    float* __restrict__ C, int M, int N, int K, int remap) {
  __shared__ unsigned short As[128 * 32];
  __shared__ unsigned short Bs[128 * 32];
  const int tid = threadIdx.x;
  const int wv = tid >> 6, l = tid & 63;
  const int row0 = blockIdx.y * 128, col0 = blockIdx.x * 128;
  const int wm = (wv & 1) * 64, wn = (wv >> 1) * 64;
  const int sr = l >> 2, sc = (l & 3) * 8;
  const int fr = l & 15, fq = (l >> 4) * 8;

  f32x4 acc[4][4];
#pragma unroll
  for (int i = 0; i < 4; i++)
#pragma unroll
    for (int j = 0; j < 4; j++) acc[i][j] = (f32x4){0.f, 0.f, 0.f, 0.f};

  for (int k0 = 0; k0 < K; k0 += 32) {
    const int kk = k0 + sc;
    const size_t koff = remap ? ((size_t)(kk >> 6) * 128 + (kk & 63)) : (size_t)kk;
#pragma unroll
    for (int j = wv; j < 8; j += 4) {
      glds16(A  + (size_t)(row0 + j * 16 + sr) * lda + koff, (char*)As + j * 1024);
      glds16(Bt + (size_t)(col0 + j * 16 + sr) * K   + kk,   (char*)Bs + j * 1024);
    }
    __syncthreads();
    bf16x8 af[4], bfr[4];
#pragma unroll
    for (int mi = 0; mi < 4; mi++)
      af[mi] = *(const bf16x8*)&As[(wm + mi * 16 + fr) * 32 + fq];
#pragma unroll
    for (int ni = 0; ni < 4; ni++)
      bfr[ni] = *(const bf16x8*)&Bs[(wn + ni * 16 + fr) * 32 + fq];
#pragma unroll
    for (int mi = 0; mi < 4; mi++)
#pragma unroll
      for (int ni = 0; ni < 4; ni++)
        acc[mi][ni] = __builtin_amdgcn_mfma_f32_16x16x32_bf16(af[mi], bfr[ni], acc[mi][ni], 0, 0, 0);
    __syncthreads();
  }
  const int q = l >> 4;
#pragma unroll
  for (int mi = 0; mi < 4; mi++)
#pragma unroll
    for (int ni = 0; ni < 4; ni++) {
      int col = col0 + wn + ni * 16 + fr;
      float bs = bias[col];
#pragma unroll
      for (int r = 0; r < 4; r++) {
        int row = row0 + wm + mi * 16 + q * 4 + r;
        C[(size_t)row * N + col] = acc[mi][ni][r] + bs;
      }
    }
}

// ---------------- conversions ----------------
// W (f32, [K][N]) -> Wt (bf16, [N][K])
__global__ __launch_bounds__(256) void tcvt(const float* __restrict__ W,
                                            unsigned short* __restrict__ Wt, int K, int N) {
  __shared__ unsigned short t[64][65];
  const int n0 = blockIdx.x * 64, k0 = blockIdx.y * 64;
  const int c = threadIdx.x & 63, r0 = threadIdx.x >> 6;
#pragma unroll
  for (int rr = r0; rr < 64; rr += 4)
    t[c][rr] = f2bf(W[(size_t)(k0 + rr) * N + n0 + c]);
  __syncthreads();
#pragma unroll
  for (int rr = r0; rr < 64; rr += 4)
    Wt[(size_t)(n0 + rr) * K + k0 + c] = t[rr][c];
}

// W (f32, [K][N]) -> Wh,Wl (bf16 hi/lo RNE split, [N][K])
__global__ __launch_bounds__(256) void tcvt_split(const float* __restrict__ W,
                                                  unsigned short* __restrict__ Wh,
                                                  unsigned short* __restrict__ Wl,
                                                  int K, int N) {
  __shared__ float t[64][65];
  const int n0 = blockIdx.x * 64, k0 = blockIdx.y * 64;
  const int c = threadIdx.x & 63, r0 = threadIdx.x >> 6;
#pragma unroll
  for (int rr = r0; rr < 64; rr += 4)
    t[c][rr] = W[(size_t)(k0 + rr) * N + n0 + c];
  __syncthreads();
#pragma unroll
  for (int rr = r0; rr < 64; rr += 4) {
    float f = t[rr][c];
    unsigned short h = f2bf(f);
    size_t o = (size_t)(n0 + rr) * K + k0 + c;
    Wh[o] = h;
    Wl[o] = f2bf(f - bf2f(h));
  }
}

__global__ __launch_bounds__(256) void sigmoid_k(float* __restrict__ p, int n) {
  int i = blockIdx.x * 256 + threadIdx.x;
  if (i < n) p[i] = 1.f / (1.f + expf(-p[i]));
}

__global__ __launch_bounds__(256) void normalize_qk(float* __restrict__ qkv) {
  const int idx = blockIdx.x * 4 + (threadIdx.x >> 6);
  const int l = threadIdx.x & 63;
  const int rowBT = idx >> 5;
  const int rem = idx & 31;
  const int which = rem >> 4;
  const int h = rem & 15;
  const size_t addr = (size_t)rowBT * 3072 + (size_t)which * 1024 + h * 64 + l;
  float v = qkv[addr];
  float ss = wave_sum(v * v);
  float sc = 1.f / fmaxf(sqrtf(ss), 1e-12f);
  qkv[addr] = v * sc;
}

// ---------------- Titans recurrence (single wave per (b,h), glds-staged,
// double-buffered). Lane l owns S[:,l], M[:,l]. Writes LN(o) as bf16 into
// head h's OWN v half: shorts 4096 + h*128 + l from the row base.
__global__ __launch_bounds__(64) void titans_rec(
    float* __restrict__ qkv, const float* __restrict__ pg,
    const float* __restrict__ w, const float* __restrict__ bparm) {
  const int bh = blockIdx.x, b = bh >> 4, h = bh & 15;
  const int l = threadIdx.x;

  __shared__ float qs[2][CSZ][DD];
  __shared__ float ks[2][CSZ][DD];
  __shared__ float vs[2][CSZ][DD];

  const float w_l = w[h * DD + l];
  const float b_l = bparm[h * DD + l];

  float* qk = qkv + (size_t)(b * TT) * 3072 + h * DD;
  const float* pbase = pg + (size_t)(b * TT) * 48 + h * 3;

  const int srow = l >> 4;
  const int soff = (l & 15) * 4;
  const int pt = l / 3, pj = l - pt * 3;

  v2f S[32], M[32];
#pragma unroll
  for (int i = 0; i < 32; i++) { S[i] = (v2f){0.f, 0.f}; M[i] = (v2f){0.f, 0.f}; }

  auto stage = [&](int row0, int bb) {
#pragma unroll
    for (int j = 0; j < 4; j++) {
      size_t go = (size_t)(row0 + j * 4 + srow) * 3072 + soff;
      glds16(qk + go,        &qs[bb][j * 4][0]);
      glds16(qk + go + 1024, &ks[bb][j * 4][0]);
      glds16(qk + go + 2048, &vs[bb][j * 4][0]);
    }
  };
  auto loadp = [&](int row0) -> float {
    float r = 0.f;
    if (l < 48) r = pbase[(size_t)(row0 + pt) * 48 + pj];
    return r;
  };

  stage(0, 0);
  float pv = loadp(0);

  for (int nt = 0; nt < NTC; nt++) {
    const int bb = nt & 1;
    const int row0 = nt * CSZ;

    __builtin_amdgcn_s_waitcnt(0);
    __syncthreads();
    if (nt + 1 < NTC) stage(row0 + CSZ, bb ^ 1);
    float pvn = (nt + 1 < NTC) ? loadp(row0 + CSZ) : 0.f;

    float dkh[CSZ];
#pragma unroll 2
    for (int c = 0; c < CSZ; c++) {
      const float4* k4 = (const float4*)&ks[bb][c][0];
      v2f a0 = (v2f){0.f, 0.f}, a1 = (v2f){0.f, 0.f};
#pragma unroll
      for (int i = 0; i < 16; i++) {
        float4 kk = k4[i];
        v2f klo = (v2f){kk.x, kk.y}, khi = (v2f){kk.z, kk.w};
        a0 += klo * S[2 * i];
        a1 += khi * S[2 * i + 1];
      }
      float kh = a0.x + a0.y + a1.x + a1.y;
      float mu = wave_sum(kh) * (1.f / 64.f);
      float xc = kh - mu;
      float var = wave_sum(xc * xc) * (1.f / 64.f);
      float rstd = rsqrtf(var + EPSF);
      float xhat = xc * rstd;
      float dy = 2.f * (xhat * w_l + b_l - vs[bb][c][l]);
      float wdy = dy * w_l;
      float c1 = wave_sum(xhat * wdy) * (1.f / 64.f);
      float c2 = wave_sum(wdy) * (1.f / 64.f);
      dkh[c] = (wdy - xhat * c1 - c2) * rstd;
    }

    float o[CSZ];
#pragma unroll 1
    for (int t = 0; t < CSZ; t++) {
      float th = __shfl(pv, 3 * t, 64);
      float al = __shfl(pv, 3 * t + 1, 64);
      float et = __shfl(pv, 3 * t + 2, 64);
      const float4* k4 = (const float4*)&ks[bb][t][0];
      const float4* q4 = (const float4*)&qs[bb][t][0];
      const float a = th * dkh[t];
      const v2f av = (v2f){a, a};
      const v2f ev = (v2f){et, et};
      const float oma = 1.f - al;
      const v2f ov = (v2f){oma, oma};
      v2f o0 = (v2f){0.f, 0.f}, o1 = (v2f){0.f, 0.f};
#pragma unroll
      for (int i = 0; i < 16; i++) {
        float4 kk = k4[i];
        float4 qq = q4[i];
        v2f klo = (v2f){kk.x, kk.y}, khi = (v2f){kk.z, kk.w};
        v2f qlo = (v2f){qq.x, qq.y}, qhi = (v2f){qq.z, qq.w};
        M[2 * i] = ev * M[2 * i] - av * klo;
        S[2 * i] = ov * S[2 * i] + M[2 * i];
        o0 += qlo * S[2 * i];
        M[2 * i + 1] = ev * M[2 * i + 1] - av * khi;
        S[2 * i + 1] = ov * S[2 * i + 1] + M[2 * i + 1];
        o1 += qhi * S[2 * i + 1];
      }
      o[t] = o0.x + o0.y + o1.x + o1.y;
    }

#pragma unroll 4
    for (int t = 0; t < CSZ; t++) {
      float x = o[t];
      float mu = wave_sum(x) * (1.f / 64.f);
      float xc = x - mu;
      float var = wave_sum(xc * xc) * (1.f / 64.f);
      float rstd = rsqrtf(var + EPSF);
      float y = xc * rstd * w_l + b_l;
      unsigned short* rowb = (unsigned short*)(qkv + (size_t)(b * TT + row0 + t) * 3072);
      rowb[4096 + h * 128 + l] = f2bf(y);
    }
    pv = pvn;
  }
}

extern "C" void kernel_launch(void* const* d_in, const int* in_sizes, int n_in,
                              void* d_out, int out_size, void* d_ws, size_t ws_size,
                              hipStream_t stream) {
  const float* x      = (const float*)d_in[0];
  const float* W_attn = (const float*)d_in[1];
  const float* b_attn = (const float*)d_in[2];
  const float* W_parm = (const float*)d_in[3];
  const float* b_parm = (const float*)d_in[4];
  const float* W_proj = (const float*)d_in[5];
  const float* b_proj = (const float*)d_in[6];
  const float* w      = (const float*)d_in[7];
  const float* bb     = (const float*)d_in[8];
  float* out = (float*)d_out;

  const int M = BB * TT;  // 8192

  // d_ws: qkv f32 (96MB) | pbf (1.5MB) | Wtp bf16 (2MB)  -- same footprint as r4/r5
  float* qkv = (float*)d_ws;
  float* pbf = qkv + (size_t)M * 3072;
  unsigned short* Wtp = (unsigned short*)(pbf + (size_t)M * 48);

  // d_out transients (dead before the final GEMM): Wh [0,6MB), Wl [6,12MB)
  unsigned short* Wh = (unsigned short*)d_out;
  unsigned short* Wl = (unsigned short*)d_out + (size_t)3072 * 1024;

  // 1) weight conversions
  tcvt_split<<<dim3(3072 / 64, CCH / 64), 256, 0, stream>>>(W_attn, Wh, Wl, CCH, 3072);
  tcvt<<<dim3(CCH / 64, CCH / 64), 256, 0, stream>>>(W_proj, Wtp, CCH, CCH);

  // 2) qkv = x @ W_attn + b_attn  (split-precision MFMA, ~2^-16 rel error)
  gemm_split<<<dim3(3072 / 128, M / 128), 256, 0, stream>>>(x, Wh, Wl, b_attn, qkv, M, 3072, CCH);

  // 3) p = sigmoid(x @ W_param + b_param)  (fp32)
  gemm_f32<<<dim3(1, M / 128), 256, 0, stream>>>(x, CCH, W_parm, b_parm, pbf, M, 48, CCH);
  sigmoid_k<<<(M * 48 + 255) / 256, 256, 0, stream>>>(pbf, M * 48);

  // 4) L2-normalize q,k (fp32)
  normalize_qk<<<(M * 2 * HH) / 4, 256, 0, stream>>>(qkv);

  // 5) recurrence (fp32 state; writes bf16 o per-head-packed into v-slot)
  titans_rec<<<BB * HH, 64, 0, stream>>>(qkv, pbf, w, bb);

  // 6) out = o @ W_proj + b_proj  (bf16 MFMA; A = per-head-packed bf16 o, remap=1)
  gemm_bf16<<<dim3(CCH / 128, M / 128), 256, 0, stream>>>(
      (unsigned short*)qkv + 4096, 6144, Wtp, b_proj, out, M, CCH, CCH, 1);
}